// Round 1
// baseline (151.271 us; speedup 1.0000x reference)
//
#include <hip/hip_runtime.h>

#define N_TERMS 2048
#define NCOL 4096
#define NC4 (NCOL / 4)            // 1024 float4 per row
#define NCHUNK 64
#define ROWS_PER_CHUNK (N_TERMS / NCHUNK)  // 32

// ---------------------------------------------------------------------------
// Kernel 1: partial column-wise sum of |x| over row chunks (skipping row 0).
// grid: (NC4/256, NCHUNK), block: 256. partial is chunk-major [NCHUNK][NCOL].
// ---------------------------------------------------------------------------
__global__ void k_partial_abs(const float* __restrict__ x, float* __restrict__ partial) {
    int col4 = blockIdx.x * blockDim.x + threadIdx.x;  // [0, 1024)
    int chunk = blockIdx.y;
    int r0 = chunk * ROWS_PER_CHUNK;
    int r1 = r0 + ROWS_PER_CHUNK;
    if (r0 == 0) r0 = 1;  // abs_sum excludes the center row
    const float4* x4 = (const float4*)x;
    float4 acc = {0.f, 0.f, 0.f, 0.f};
    for (int r = r0; r < r1; ++r) {
        float4 v = x4[(long)r * NC4 + col4];
        acc.x += fabsf(v.x);
        acc.y += fabsf(v.y);
        acc.z += fabsf(v.z);
        acc.w += fabsf(v.w);
    }
    ((float4*)partial)[chunk * NC4 + col4] = acc;
}

// ---------------------------------------------------------------------------
// Kernel 2: per-column stats. Reduce the 64 partials, compute lam/delta etc.,
// write output row 0 (center), and per-column scale / delta-half / cross flag.
// grid: NCOL/256, block: 256.
// ---------------------------------------------------------------------------
__global__ void k_stats(const float* __restrict__ x, const float* __restrict__ partial,
                        float* __restrict__ out0, float* __restrict__ scale,
                        float* __restrict__ dhalf, int* __restrict__ crossflag) {
    int c = blockIdx.x * blockDim.x + threadIdx.x;
    float s = 0.f;
    for (int k = 0; k < NCHUNK; ++k) s += partial[k * NCOL + c];
    float x0 = x[c];
    float u = x0 + s;
    float l = x0 - s;
    bool cross = (l * u) < 0.0f;
    bool pos = (l >= 0.0f);
    float denom = u - l;
    float lam = (pos ? 1.0f : 0.0f) +
                (cross ? ((denom != 0.0f) ? u / denom : 0.5f) : 0.0f);
    float delta = fmaxf(-lam * l, (1.0f - lam) * u);
    float crossf = cross ? 1.0f : 0.0f;
    float posf = pos ? 1.0f : 0.0f;
    out0[c] = (delta * 0.5f + lam * x0) * crossf + x0 * posf;
    scale[c] = lam * crossf + posf;
    dhalf[c] = delta * 0.5f * crossf;
    crossflag[c] = cross ? 1 : 0;
}

// ---------------------------------------------------------------------------
// Kernel 3: exclusive prefix sum of cross flags over 4096 columns -> the tail
// row index each column's new error term lands on. Single block of 256.
// ---------------------------------------------------------------------------
__global__ void k_prefix(const int* __restrict__ crossflag, int* __restrict__ rowtarget) {
    const int T = 256;
    const int PER = NCOL / T;  // 16
    __shared__ int tsum[T];
    int t = threadIdx.x;
    int base = t * PER;
    int ex[PER];
    int run = 0;
    for (int i = 0; i < PER; ++i) {
        ex[i] = run;
        run += crossflag[base + i];
    }
    tsum[t] = run;
    __syncthreads();
    // Hillis-Steele inclusive scan over 256 thread totals
    for (int off = 1; off < T; off <<= 1) {
        int v = 0;
        if (t >= off) v = tsum[t - off];
        __syncthreads();
        tsum[t] += v;
        __syncthreads();
    }
    int excl = (t == 0) ? 0 : tsum[t - 1];
    for (int i = 0; i < PER; ++i) rowtarget[base + i] = N_TERMS + excl + ex[i];
}

// ---------------------------------------------------------------------------
// Kernel 4: write rows 1..6143. Rows 1..2047: gens = x * scale[col].
// Rows 2048..6143: dhalf[col] on the (rowtarget[col]==row) slot, else 0.
// One float4 per thread; grid covers exactly (N_TERMS+NCOL-1)*NC4 float4s.
// ---------------------------------------------------------------------------
__global__ void k_write(const float* __restrict__ x, const float* __restrict__ scale,
                        const float* __restrict__ dhalf, const int* __restrict__ rowtarget,
                        float* __restrict__ out) {
    long gidx = (long)blockIdx.x * blockDim.x + threadIdx.x;
    int row = (int)(gidx >> 10) + 1;   // NC4 == 1024
    int col4 = (int)(gidx & 1023);
    const float4* x4 = (const float4*)x;
    float4* o4 = (float4*)out;
    if (row < N_TERMS) {
        float4 v = x4[(long)row * NC4 + col4];
        float4 sc = ((const float4*)scale)[col4];
        v.x *= sc.x; v.y *= sc.y; v.z *= sc.z; v.w *= sc.w;
        o4[(long)row * NC4 + col4] = v;
    } else {
        int4 rt = ((const int4*)rowtarget)[col4];
        float4 dh = ((const float4*)dhalf)[col4];
        float4 v;
        v.x = (rt.x == row) ? dh.x : 0.0f;
        v.y = (rt.y == row) ? dh.y : 0.0f;
        v.z = (rt.z == row) ? dh.z : 0.0f;
        v.w = (rt.w == row) ? dh.w : 0.0f;
        o4[(long)row * NC4 + col4] = v;
    }
}

extern "C" void kernel_launch(void* const* d_in, const int* in_sizes, int n_in,
                              void* d_out, int out_size, void* d_ws, size_t ws_size,
                              hipStream_t stream) {
    const float* x = (const float*)d_in[0];
    float* out = (float*)d_out;

    float* ws = (float*)d_ws;
    float* partial   = ws;                       // 64*4096 floats = 1 MB
    float* scale     = partial + NCHUNK * NCOL;  // 4096 floats
    float* dhalf     = scale + NCOL;             // 4096 floats
    int*   crossflag = (int*)(dhalf + NCOL);     // 4096 ints
    int*   rowtarget = crossflag + NCOL;         // 4096 ints

    k_partial_abs<<<dim3(NC4 / 256, NCHUNK), 256, 0, stream>>>(x, partial);
    k_stats<<<NCOL / 256, 256, 0, stream>>>(x, partial, out, scale, dhalf, crossflag);
    k_prefix<<<1, 256, 0, stream>>>(crossflag, rowtarget);

    const long total4 = (long)(N_TERMS + NCOL - 1) * NC4;  // 6143*1024
    const int blocks = (int)((total4 + 255) / 256);        // 24572 exactly
    k_write<<<blocks, 256, 0, stream>>>(x, scale, dhalf, rowtarget, out);
}

// Round 2
// 140.600 us; speedup vs baseline: 1.0759x; 1.0759x over previous
//
#include <hip/hip_runtime.h>

#define N_TERMS 2048
#define NCOL 4096
#define NC4 (NCOL / 4)            // 1024 float4 per row
#define NCHUNK 128
#define ROWS_PER_CHUNK (N_TERMS / NCHUNK)  // 16

// ---------------------------------------------------------------------------
// Kernel 1: partial column-wise sum of |x| over row chunks (skipping row 0).
// grid: (NC4/256 = 4, NCHUNK = 128) = 512 blocks -> 2 blocks/CU, 8 waves/CU.
// Each thread: 16 independent float4 loads -> enough MLP to hide HBM latency.
// partial is chunk-major [NCHUNK][NCOL].
// ---------------------------------------------------------------------------
__global__ void k_partial_abs(const float* __restrict__ x, float* __restrict__ partial) {
    int col4 = blockIdx.x * blockDim.x + threadIdx.x;  // [0, 1024)
    int chunk = blockIdx.y;
    int r0 = chunk * ROWS_PER_CHUNK;
    int r1 = r0 + ROWS_PER_CHUNK;
    if (r0 == 0) r0 = 1;  // abs_sum excludes the center row
    const float4* x4 = (const float4*)x;
    float4 acc = {0.f, 0.f, 0.f, 0.f};
#pragma unroll
    for (int r = r0; r < r1; ++r) {
        float4 v = x4[(long)r * NC4 + col4];
        acc.x += fabsf(v.x);
        acc.y += fabsf(v.y);
        acc.z += fabsf(v.z);
        acc.w += fabsf(v.w);
    }
    ((float4*)partial)[chunk * NC4 + col4] = acc;
}

// ---------------------------------------------------------------------------
// Kernel 2: per-column stats. Reduce the 128 partials, compute lam/delta etc.,
// write output row 0 (center), and per-column scale / delta-half / cross flag.
// grid: NCOL/256 = 16 blocks, block: 256. Reads are coalesced across threads.
// ---------------------------------------------------------------------------
__global__ void k_stats(const float* __restrict__ x, const float* __restrict__ partial,
                        float* __restrict__ out0, float* __restrict__ scale,
                        float* __restrict__ dhalf, int* __restrict__ crossflag) {
    int c = blockIdx.x * blockDim.x + threadIdx.x;
    float s0 = 0.f, s1 = 0.f, s2 = 0.f, s3 = 0.f;
#pragma unroll 4
    for (int k = 0; k < NCHUNK; k += 4) {
        s0 += partial[(k + 0) * NCOL + c];
        s1 += partial[(k + 1) * NCOL + c];
        s2 += partial[(k + 2) * NCOL + c];
        s3 += partial[(k + 3) * NCOL + c];
    }
    float s = (s0 + s1) + (s2 + s3);
    float x0 = x[c];
    float u = x0 + s;
    float l = x0 - s;
    bool cross = (l * u) < 0.0f;
    bool pos = (l >= 0.0f);
    float denom = u - l;
    float lam = (pos ? 1.0f : 0.0f) +
                (cross ? ((denom != 0.0f) ? u / denom : 0.5f) : 0.0f);
    float delta = fmaxf(-lam * l, (1.0f - lam) * u);
    float crossf = cross ? 1.0f : 0.0f;
    float posf = pos ? 1.0f : 0.0f;
    out0[c] = (delta * 0.5f + lam * x0) * crossf + x0 * posf;
    scale[c] = lam * crossf + posf;
    dhalf[c] = delta * 0.5f * crossf;
    crossflag[c] = cross ? 1 : 0;
}

// ---------------------------------------------------------------------------
// Kernel 3: exclusive prefix sum of cross flags over 4096 columns -> the tail
// row index each column's new error term lands on. Single block of 256.
// ---------------------------------------------------------------------------
__global__ void k_prefix(const int* __restrict__ crossflag, int* __restrict__ rowtarget) {
    const int T = 256;
    const int PER = NCOL / T;  // 16
    __shared__ int tsum[T];
    int t = threadIdx.x;
    int base = t * PER;
    int ex[PER];
    int run = 0;
#pragma unroll
    for (int i = 0; i < PER; ++i) {
        ex[i] = run;
        run += crossflag[base + i];
    }
    tsum[t] = run;
    __syncthreads();
    // Hillis-Steele inclusive scan over 256 thread totals
    for (int off = 1; off < T; off <<= 1) {
        int v = 0;
        if (t >= off) v = tsum[t - off];
        __syncthreads();
        tsum[t] += v;
        __syncthreads();
    }
    int excl = (t == 0) ? 0 : tsum[t - 1];
#pragma unroll
    for (int i = 0; i < PER; ++i) rowtarget[base + i] = N_TERMS + excl + ex[i];
}

// ---------------------------------------------------------------------------
// Kernel 4: write rows 1..6143. Rows 1..2047: gens = x * scale[col].
// Rows 2048..6143: dhalf[col] on the (rowtarget[col]==row) slot, else 0.
// One float4 per thread; grid covers exactly (N_TERMS+NCOL-1)*NC4 float4s.
// ---------------------------------------------------------------------------
__global__ void k_write(const float* __restrict__ x, const float* __restrict__ scale,
                        const float* __restrict__ dhalf, const int* __restrict__ rowtarget,
                        float* __restrict__ out) {
    long gidx = (long)blockIdx.x * blockDim.x + threadIdx.x;
    int row = (int)(gidx >> 10) + 1;   // NC4 == 1024
    int col4 = (int)(gidx & 1023);
    const float4* x4 = (const float4*)x;
    float4* o4 = (float4*)out;
    if (row < N_TERMS) {
        float4 v = x4[(long)row * NC4 + col4];
        float4 sc = ((const float4*)scale)[col4];
        v.x *= sc.x; v.y *= sc.y; v.z *= sc.z; v.w *= sc.w;
        o4[(long)row * NC4 + col4] = v;
    } else {
        int4 rt = ((const int4*)rowtarget)[col4];
        float4 dh = ((const float4*)dhalf)[col4];
        float4 v;
        v.x = (rt.x == row) ? dh.x : 0.0f;
        v.y = (rt.y == row) ? dh.y : 0.0f;
        v.z = (rt.z == row) ? dh.z : 0.0f;
        v.w = (rt.w == row) ? dh.w : 0.0f;
        o4[(long)row * NC4 + col4] = v;
    }
}

extern "C" void kernel_launch(void* const* d_in, const int* in_sizes, int n_in,
                              void* d_out, int out_size, void* d_ws, size_t ws_size,
                              hipStream_t stream) {
    const float* x = (const float*)d_in[0];
    float* out = (float*)d_out;

    float* ws = (float*)d_ws;
    float* partial   = ws;                       // 128*4096 floats = 2 MB
    float* scale     = partial + NCHUNK * NCOL;  // 4096 floats
    float* dhalf     = scale + NCOL;             // 4096 floats
    int*   crossflag = (int*)(dhalf + NCOL);     // 4096 ints
    int*   rowtarget = crossflag + NCOL;         // 4096 ints

    k_partial_abs<<<dim3(NC4 / 256, NCHUNK), 256, 0, stream>>>(x, partial);
    k_stats<<<NCOL / 256, 256, 0, stream>>>(x, partial, out, scale, dhalf, crossflag);
    k_prefix<<<1, 256, 0, stream>>>(crossflag, rowtarget);

    const long total4 = (long)(N_TERMS + NCOL - 1) * NC4;  // 6143*1024
    const int blocks = (int)((total4 + 255) / 256);        // 24572 exactly
    k_write<<<blocks, 256, 0, stream>>>(x, scale, dhalf, rowtarget, out);
}